// Round 2
// baseline (2523.393 us; speedup 1.0000x reference)
//
#include <hip/hip_runtime.h>
#include <stdint.h>

// BinHD: samples [8192,10000] f32 {0,1}, classes [1000,10000] f32 {0,1}
// out [8192,1000] f32 = Hamming = popcount(xor) over bit-packed rows (exact).
// Bit PACKING ORDER is an arbitrary but consistent permutation of dims
// (Hamming is permutation-invariant), which lets pack use wave ballots.
#define N_ROWS 8192
#define C_CLS  1000
#define D_DIM  10000
#define W64P   160            // u64 words per packed row, padded (157 used)
#define W32P   (W64P * 2)     // 320 u32 words per packed row
#define BSTR   132            // B LDS row stride (pads 128 -> kills conflicts)
#define NCHUNK 20             // 20 chunks x 16 u32 words = 320

// ---------------------------------------------------------------------------
// Kernel 1: bit-pack via float4 + 4 wave ballots. One wave per row.
// Iter covers 256 dims: lane i reads float4 at dim 256*it + 4*i; ballot k
// packs bit (4*i+k). 39 full iters + 16-dim tail. Writes all W64P words.
// ---------------------------------------------------------------------------
__global__ __launch_bounds__(256) void pack_kernel(
    const float* __restrict__ samples, const float* __restrict__ classes,
    unsigned long long* __restrict__ pA, unsigned long long* __restrict__ pB)
{
    int gwave = (blockIdx.x * 256 + threadIdx.x) >> 6;
    int lane  = threadIdx.x & 63;
    if (gwave >= N_ROWS + C_CLS) return;   // wave-uniform exit

    const float* src;
    unsigned long long* dst;
    if (gwave < N_ROWS) {
        src = samples + (size_t)gwave * D_DIM;
        dst = pA + (size_t)gwave * W64P;
    } else {
        int r = gwave - N_ROWS;
        src = classes + (size_t)r * D_DIM;
        dst = pB + (size_t)r * W64P;
    }

    #pragma unroll 4
    for (int it = 0; it < 39; ++it) {       // dims 0..9983 -> words 0..155
        float4 v = *(const float4*)(src + it * 256 + lane * 4);
        unsigned long long m0 = __ballot(v.x > 0.5f);
        unsigned long long m1 = __ballot(v.y > 0.5f);
        unsigned long long m2 = __ballot(v.z > 0.5f);
        unsigned long long m3 = __ballot(v.w > 0.5f);
        if (lane < 2) {
            ulonglong2 st;
            st.x = lane ? m2 : m0;
            st.y = lane ? m3 : m1;
            *(ulonglong2*)(dst + it * 4 + lane * 2) = st;
        }
    }
    {   // tail: dims 9984..9999 -> words 156..159 (mostly zero)
        float4 v = make_float4(0.f, 0.f, 0.f, 0.f);
        if (lane < 4) v = *(const float4*)(src + 9984 + lane * 4);
        unsigned long long m0 = __ballot(v.x > 0.5f);
        unsigned long long m1 = __ballot(v.y > 0.5f);
        unsigned long long m2 = __ballot(v.z > 0.5f);
        unsigned long long m3 = __ballot(v.w > 0.5f);
        if (lane < 2) {
            ulonglong2 st;
            st.x = lane ? m2 : m0;
            st.y = lane ? m3 : m1;
            *(ulonglong2*)(dst + 156 + lane * 2) = st;
        }
    }
}

// ---------------------------------------------------------------------------
// Kernel 2: Hamming GEMM, double-buffered LDS, ONE barrier per chunk.
// Block tile 128x128, 256 threads, 8x8 accumulators per thread.
// Thread cols = [tcol..tcol+3] U [tcol+32..tcol+35] -> dense 16B stores.
// ---------------------------------------------------------------------------
__global__ __launch_bounds__(256, 2) void hd_kernel(
    const uint32_t* __restrict__ pA, const uint32_t* __restrict__ pB,
    float* __restrict__ out)
{
    __shared__ uint32_t As[2][128 * 16];
    __shared__ uint32_t Bs[2][16 * BSTR];

    const int tid  = threadIdx.x;
    const int row0 = blockIdx.x * 128;
    const int col0 = blockIdx.y * 128;

    const int w    = tid >> 6;
    const int lane = tid & 63;
    const int lx   = lane & 7;
    const int ly   = lane >> 3;
    const int wx   = w & 1, wy = w >> 1;
    const int trow = wy * 64 + ly * 8;       // thread row base in 128-tile
    const int tcol = wx * 64 + lx * 4;       // thread col base (dense mapping)
    const int sw   = ly & 3;                 // A read swizzle key

    // staging indices (wave-invariant per thread)
    const int rr0 = tid >> 2, g0 = tid & 3;          // i=0
    const int rr1 = (tid + 256) >> 2, g1 = tid & 3;  // i=1

    const uint32_t* aA0 = pA + (size_t)(row0 + rr0) * W32P + g0 * 4;
    const uint32_t* aA1 = pA + (size_t)(row0 + rr1) * W32P + g1 * 4;
    const bool bok0 = (col0 + rr0) < C_CLS;
    const bool bok1 = (col0 + rr1) < C_CLS;
    const uint32_t* aB0 = pB + (size_t)(bok0 ? (col0 + rr0) : 0) * W32P + g0 * 4;
    const uint32_t* aB1 = pB + (size_t)(bok1 ? (col0 + rr1) : 0) * W32P + g1 * 4;

    uint32_t acc[8][8];
    #pragma unroll
    for (int r = 0; r < 8; ++r)
        #pragma unroll
        for (int c = 0; c < 8; ++c) acc[r][c] = 0;

    // ---- prologue: chunk 0 -> buf 0 ----
    uint4 av0 = *(const uint4*)aA0;
    uint4 av1 = *(const uint4*)aA1;
    uint4 bv0 = bok0 ? *(const uint4*)aB0 : make_uint4(0u,0u,0u,0u);
    uint4 bv1 = bok1 ? *(const uint4*)aB1 : make_uint4(0u,0u,0u,0u);

    *(uint4*)&As[0][rr0 * 16 + ((g0 ^ ((rr0 >> 3) & 3)) << 2)] = av0;
    *(uint4*)&As[0][rr1 * 16 + ((g1 ^ ((rr1 >> 3) & 3)) << 2)] = av1;
    Bs[0][(g0 * 4 + 0) * BSTR + rr0] = bv0.x;
    Bs[0][(g0 * 4 + 1) * BSTR + rr0] = bv0.y;
    Bs[0][(g0 * 4 + 2) * BSTR + rr0] = bv0.z;
    Bs[0][(g0 * 4 + 3) * BSTR + rr0] = bv0.w;
    Bs[0][(g1 * 4 + 0) * BSTR + rr1] = bv1.x;
    Bs[0][(g1 * 4 + 1) * BSTR + rr1] = bv1.y;
    Bs[0][(g1 * 4 + 2) * BSTR + rr1] = bv1.z;
    Bs[0][(g1 * 4 + 3) * BSTR + rr1] = bv1.w;
    __syncthreads();

    for (int ch = 0; ch < NCHUNK; ++ch) {
        const int cur = ch & 1;
        // ---- issue next chunk's global loads (in flight across compute) ----
        if (ch + 1 < NCHUNK) {
            const int off = (ch + 1) * 16;
            av0 = *(const uint4*)(aA0 + off);
            av1 = *(const uint4*)(aA1 + off);
            bv0 = bok0 ? *(const uint4*)(aB0 + off) : make_uint4(0u,0u,0u,0u);
            bv1 = bok1 ? *(const uint4*)(aB1 + off) : make_uint4(0u,0u,0u,0u);
        }

        // ---- compute chunk ch from buf[cur] ----
        #pragma unroll
        for (int g = 0; g < 4; ++g) {
            uint4 a[8];
            #pragma unroll
            for (int r = 0; r < 8; ++r)
                a[r] = *(const uint4*)&As[cur][(trow + r) * 16 + ((g ^ sw) << 2)];
            #pragma unroll
            for (int j = 0; j < 4; ++j) {
                uint4 b0 = *(const uint4*)&Bs[cur][(g * 4 + j) * BSTR + tcol];
                uint4 b1 = *(const uint4*)&Bs[cur][(g * 4 + j) * BSTR + tcol + 32];
                #pragma unroll
                for (int r = 0; r < 8; ++r) {
                    uint32_t aw = (j == 0) ? a[r].x : (j == 1) ? a[r].y
                                : (j == 2) ? a[r].z : a[r].w;
                    acc[r][0] += __popc(aw ^ b0.x);
                    acc[r][1] += __popc(aw ^ b0.y);
                    acc[r][2] += __popc(aw ^ b0.z);
                    acc[r][3] += __popc(aw ^ b0.w);
                    acc[r][4] += __popc(aw ^ b1.x);
                    acc[r][5] += __popc(aw ^ b1.y);
                    acc[r][6] += __popc(aw ^ b1.z);
                    acc[r][7] += __popc(aw ^ b1.w);
                }
            }
        }

        // ---- stage next chunk into the other buffer; single barrier ----
        if (ch + 1 < NCHUNK) {
            const int nxt = cur ^ 1;
            *(uint4*)&As[nxt][rr0 * 16 + ((g0 ^ ((rr0 >> 3) & 3)) << 2)] = av0;
            *(uint4*)&As[nxt][rr1 * 16 + ((g1 ^ ((rr1 >> 3) & 3)) << 2)] = av1;
            Bs[nxt][(g0 * 4 + 0) * BSTR + rr0] = bv0.x;
            Bs[nxt][(g0 * 4 + 1) * BSTR + rr0] = bv0.y;
            Bs[nxt][(g0 * 4 + 2) * BSTR + rr0] = bv0.z;
            Bs[nxt][(g0 * 4 + 3) * BSTR + rr0] = bv0.w;
            Bs[nxt][(g1 * 4 + 0) * BSTR + rr1] = bv1.x;
            Bs[nxt][(g1 * 4 + 1) * BSTR + rr1] = bv1.y;
            Bs[nxt][(g1 * 4 + 2) * BSTR + rr1] = bv1.z;
            Bs[nxt][(g1 * 4 + 3) * BSTR + rr1] = bv1.w;
            __syncthreads();
        }
    }

    // ---- epilogue: dense float4 stores (lane-contiguous 128B lines) ----
    #pragma unroll
    for (int r = 0; r < 8; ++r) {
        int grow = row0 + trow + r;
        #pragma unroll
        for (int c4 = 0; c4 < 2; ++c4) {
            int gcol = col0 + tcol + c4 * 32;
            if (gcol < C_CLS) {
                float4 v = make_float4((float)acc[r][c4 * 4 + 0],
                                       (float)acc[r][c4 * 4 + 1],
                                       (float)acc[r][c4 * 4 + 2],
                                       (float)acc[r][c4 * 4 + 3]);
                *(float4*)(out + (size_t)grow * C_CLS + gcol) = v;
            }
        }
    }
}

extern "C" void kernel_launch(void* const* d_in, const int* in_sizes, int n_in,
                              void* d_out, int out_size, void* d_ws, size_t ws_size,
                              hipStream_t stream) {
    const float* samples = (const float*)d_in[0];   // [8192, 10000] f32
    const float* classes = (const float*)d_in[1];   // [1000, 10000] f32
    float* out = (float*)d_out;                     // [8192, 1000] f32

    unsigned long long* pA = (unsigned long long*)d_ws;          // 10.49 MB
    unsigned long long* pB = pA + (size_t)N_ROWS * W64P;         // +1.28 MB

    int waves  = N_ROWS + C_CLS;
    int blocks = (waves + 3) / 4;
    pack_kernel<<<blocks, 256, 0, stream>>>(samples, classes, pA, pB);

    dim3 grid(N_ROWS / 128, 8);              // 64 x 8 = 512 blocks
    hd_kernel<<<grid, 256, 0, stream>>>((const uint32_t*)pA, (const uint32_t*)pB, out);
}

// Round 3
// 1490.130 us; speedup vs baseline: 1.6934x; 1.6934x over previous
//
#include <hip/hip_runtime.h>
#include <stdint.h>

// BinHD: samples [8192,10000] f32 {0,1}, classes [1000,10000] f32 {0,1}
// out [8192,1000] f32 = Hamming = popcount(xor) over bit-packed rows (exact).
#define N_ROWS 8192
#define C_CLS  1000
#define D_DIM  10000
#define W64P   160            // u64 words per packed row, padded (157 used)
#define W32P   (W64P * 2)     // 320 u32 words per packed row
#define BSTR   132            // B LDS row stride (pads 128 -> kills conflicts)
#define NCHUNK 20             // 20 chunks x 16 u32 words = 320

// ---------------------------------------------------------------------------
// Kernel 1: bit-pack via float4 + 4 wave ballots. One wave per row.
// ---------------------------------------------------------------------------
__global__ __launch_bounds__(256) void pack_kernel(
    const float* __restrict__ samples, const float* __restrict__ classes,
    unsigned long long* __restrict__ pA, unsigned long long* __restrict__ pB)
{
    int gwave = (blockIdx.x * 256 + threadIdx.x) >> 6;
    int lane  = threadIdx.x & 63;
    if (gwave >= N_ROWS + C_CLS) return;   // wave-uniform exit

    const float* src;
    unsigned long long* dst;
    if (gwave < N_ROWS) {
        src = samples + (size_t)gwave * D_DIM;
        dst = pA + (size_t)gwave * W64P;
    } else {
        int r = gwave - N_ROWS;
        src = classes + (size_t)r * D_DIM;
        dst = pB + (size_t)r * W64P;
    }

    #pragma unroll 4
    for (int it = 0; it < 39; ++it) {       // dims 0..9983 -> words 0..155
        float4 v = *(const float4*)(src + it * 256 + lane * 4);
        unsigned long long m0 = __ballot(v.x > 0.5f);
        unsigned long long m1 = __ballot(v.y > 0.5f);
        unsigned long long m2 = __ballot(v.z > 0.5f);
        unsigned long long m3 = __ballot(v.w > 0.5f);
        if (lane < 2) {
            ulonglong2 st;
            st.x = lane ? m2 : m0;
            st.y = lane ? m3 : m1;
            *(ulonglong2*)(dst + it * 4 + lane * 2) = st;
        }
    }
    {   // tail: dims 9984..9999 -> words 156..159 (zero-padded)
        float4 v = make_float4(0.f, 0.f, 0.f, 0.f);
        if (lane < 4) v = *(const float4*)(src + 9984 + lane * 4);
        unsigned long long m0 = __ballot(v.x > 0.5f);
        unsigned long long m1 = __ballot(v.y > 0.5f);
        unsigned long long m2 = __ballot(v.z > 0.5f);
        unsigned long long m3 = __ballot(v.w > 0.5f);
        if (lane < 2) {
            ulonglong2 st;
            st.x = lane ? m2 : m0;
            st.y = lane ? m3 : m1;
            *(ulonglong2*)(dst + 156 + lane * 2) = st;
        }
    }
}

// ---------------------------------------------------------------------------
// Kernel 2: Hamming GEMM, double-buffered LDS, ONE barrier per chunk.
// Block tile 128x128, 256 threads, 8x8 accumulators per thread.
// NOTE: plain __launch_bounds__(256) — adding a min-waves arg capped VGPRs
// at 128 and spilled acc[] to scratch (R2: 8 GB scratch traffic, 6.7x slower).
// ---------------------------------------------------------------------------
__global__ __launch_bounds__(256) void hd_kernel(
    const uint32_t* __restrict__ pA, const uint32_t* __restrict__ pB,
    float* __restrict__ out)
{
    __shared__ uint32_t As[2][128 * 16];
    __shared__ uint32_t Bs[2][16 * BSTR];

    const int tid  = threadIdx.x;
    const int row0 = blockIdx.x * 128;
    const int col0 = blockIdx.y * 128;

    const int w    = tid >> 6;
    const int lane = tid & 63;
    const int lx   = lane & 7;
    const int ly   = lane >> 3;
    const int wx   = w & 1, wy = w >> 1;
    const int trow = wy * 64 + ly * 8;       // thread row base in 128-tile
    const int tcol = wx * 64 + lx * 4;       // thread col base (dense mapping)
    const int sw   = ly & 3;                 // A read swizzle key

    // staging indices (wave-invariant per thread)
    const int rr0 = tid >> 2, g0 = tid & 3;          // i=0
    const int rr1 = (tid + 256) >> 2, g1 = tid & 3;  // i=1

    const uint32_t* aA0 = pA + (size_t)(row0 + rr0) * W32P + g0 * 4;
    const uint32_t* aA1 = pA + (size_t)(row0 + rr1) * W32P + g1 * 4;
    const bool bok0 = (col0 + rr0) < C_CLS;
    const bool bok1 = (col0 + rr1) < C_CLS;
    const uint32_t* aB0 = pB + (size_t)(bok0 ? (col0 + rr0) : 0) * W32P + g0 * 4;
    const uint32_t* aB1 = pB + (size_t)(bok1 ? (col0 + rr1) : 0) * W32P + g1 * 4;

    uint32_t acc[8][8];
    #pragma unroll
    for (int r = 0; r < 8; ++r)
        #pragma unroll
        for (int c = 0; c < 8; ++c) acc[r][c] = 0;

    // ---- prologue: chunk 0 -> buf 0 ----
    uint4 av0 = *(const uint4*)aA0;
    uint4 av1 = *(const uint4*)aA1;
    uint4 bv0 = bok0 ? *(const uint4*)aB0 : make_uint4(0u,0u,0u,0u);
    uint4 bv1 = bok1 ? *(const uint4*)aB1 : make_uint4(0u,0u,0u,0u);

    *(uint4*)&As[0][rr0 * 16 + ((g0 ^ ((rr0 >> 3) & 3)) << 2)] = av0;
    *(uint4*)&As[0][rr1 * 16 + ((g1 ^ ((rr1 >> 3) & 3)) << 2)] = av1;
    Bs[0][(g0 * 4 + 0) * BSTR + rr0] = bv0.x;
    Bs[0][(g0 * 4 + 1) * BSTR + rr0] = bv0.y;
    Bs[0][(g0 * 4 + 2) * BSTR + rr0] = bv0.z;
    Bs[0][(g0 * 4 + 3) * BSTR + rr0] = bv0.w;
    Bs[0][(g1 * 4 + 0) * BSTR + rr1] = bv1.x;
    Bs[0][(g1 * 4 + 1) * BSTR + rr1] = bv1.y;
    Bs[0][(g1 * 4 + 2) * BSTR + rr1] = bv1.z;
    Bs[0][(g1 * 4 + 3) * BSTR + rr1] = bv1.w;
    __syncthreads();

    for (int ch = 0; ch < NCHUNK; ++ch) {
        const int cur = ch & 1;
        // ---- issue next chunk's global loads (in flight across compute) ----
        if (ch + 1 < NCHUNK) {
            const int off = (ch + 1) * 16;
            av0 = *(const uint4*)(aA0 + off);
            av1 = *(const uint4*)(aA1 + off);
            bv0 = bok0 ? *(const uint4*)(aB0 + off) : make_uint4(0u,0u,0u,0u);
            bv1 = bok1 ? *(const uint4*)(aB1 + off) : make_uint4(0u,0u,0u,0u);
        }

        // ---- compute chunk ch from buf[cur] ----
        #pragma unroll
        for (int g = 0; g < 4; ++g) {
            uint4 a[8];
            #pragma unroll
            for (int r = 0; r < 8; ++r)
                a[r] = *(const uint4*)&As[cur][(trow + r) * 16 + ((g ^ sw) << 2)];
            #pragma unroll
            for (int j = 0; j < 4; ++j) {
                uint4 b0 = *(const uint4*)&Bs[cur][(g * 4 + j) * BSTR + tcol];
                uint4 b1 = *(const uint4*)&Bs[cur][(g * 4 + j) * BSTR + tcol + 32];
                #pragma unroll
                for (int r = 0; r < 8; ++r) {
                    uint32_t aw = (j == 0) ? a[r].x : (j == 1) ? a[r].y
                                : (j == 2) ? a[r].z : a[r].w;
                    acc[r][0] += __popc(aw ^ b0.x);
                    acc[r][1] += __popc(aw ^ b0.y);
                    acc[r][2] += __popc(aw ^ b0.z);
                    acc[r][3] += __popc(aw ^ b0.w);
                    acc[r][4] += __popc(aw ^ b1.x);
                    acc[r][5] += __popc(aw ^ b1.y);
                    acc[r][6] += __popc(aw ^ b1.z);
                    acc[r][7] += __popc(aw ^ b1.w);
                }
            }
        }

        // ---- stage next chunk into the other buffer; single barrier ----
        if (ch + 1 < NCHUNK) {
            const int nxt = cur ^ 1;
            *(uint4*)&As[nxt][rr0 * 16 + ((g0 ^ ((rr0 >> 3) & 3)) << 2)] = av0;
            *(uint4*)&As[nxt][rr1 * 16 + ((g1 ^ ((rr1 >> 3) & 3)) << 2)] = av1;
            Bs[nxt][(g0 * 4 + 0) * BSTR + rr0] = bv0.x;
            Bs[nxt][(g0 * 4 + 1) * BSTR + rr0] = bv0.y;
            Bs[nxt][(g0 * 4 + 2) * BSTR + rr0] = bv0.z;
            Bs[nxt][(g0 * 4 + 3) * BSTR + rr0] = bv0.w;
            Bs[nxt][(g1 * 4 + 0) * BSTR + rr1] = bv1.x;
            Bs[nxt][(g1 * 4 + 1) * BSTR + rr1] = bv1.y;
            Bs[nxt][(g1 * 4 + 2) * BSTR + rr1] = bv1.z;
            Bs[nxt][(g1 * 4 + 3) * BSTR + rr1] = bv1.w;
            __syncthreads();
        }
    }

    // ---- epilogue: dense float4 stores (lane-contiguous 128B lines) ----
    #pragma unroll
    for (int r = 0; r < 8; ++r) {
        int grow = row0 + trow + r;
        #pragma unroll
        for (int c4 = 0; c4 < 2; ++c4) {
            int gcol = col0 + tcol + c4 * 32;
            if (gcol < C_CLS) {
                float4 v = make_float4((float)acc[r][c4 * 4 + 0],
                                       (float)acc[r][c4 * 4 + 1],
                                       (float)acc[r][c4 * 4 + 2],
                                       (float)acc[r][c4 * 4 + 3]);
                *(float4*)(out + (size_t)grow * C_CLS + gcol) = v;
            }
        }
    }
}

extern "C" void kernel_launch(void* const* d_in, const int* in_sizes, int n_in,
                              void* d_out, int out_size, void* d_ws, size_t ws_size,
                              hipStream_t stream) {
    const float* samples = (const float*)d_in[0];   // [8192, 10000] f32
    const float* classes = (const float*)d_in[1];   // [1000, 10000] f32
    float* out = (float*)d_out;                     // [8192, 1000] f32

    unsigned long long* pA = (unsigned long long*)d_ws;          // 10.49 MB
    unsigned long long* pB = pA + (size_t)N_ROWS * W64P;         // +1.28 MB

    int waves  = N_ROWS + C_CLS;
    int blocks = (waves + 3) / 4;
    pack_kernel<<<blocks, 256, 0, stream>>>(samples, classes, pA, pB);

    dim3 grid(N_ROWS / 128, 8);              // 64 x 8 = 512 blocks
    hd_kernel<<<grid, 256, 0, stream>>>((const uint32_t*)pA, (const uint32_t*)pB, out);
}